// Round 1
// baseline (431.826 us; speedup 1.0000x reference)
//
#include <hip/hip_runtime.h>
#include <math.h>

namespace {
constexpr int kB = 128;
constexpr int kV = 128256;
constexpr int kSplits = 16;
constexpr int kSplit = kV / kSplits;   // 8016
constexpr int kSplit4 = kSplit / 4;    // 2004
constexpr int kT1 = 256;
constexpr int kNB = 2048;              // histogram buckets (11-bit key prefix)
constexpr int kChunk = kNB / kT1;      // 8 buckets per thread
constexpr int kCap = 256;              // max candidates kept per split
constexpr int kTop = 64;               // max top_k

// monotonic uint key: ascending key <=> ascending float
__device__ __forceinline__ unsigned fkey(float y) {
  unsigned u = __float_as_uint(y);
  return ((int)u < 0) ? ~u : (u | 0x80000000u);
}

__global__ __launch_bounds__(kT1) void k_select(
    const float* __restrict__ logits, const float* __restrict__ temps,
    float* __restrict__ out,
    float* __restrict__ wm, float* __restrict__ wS, int* __restrict__ wc,
    float* __restrict__ wv, int* __restrict__ wi) {
  const int sp = blockIdx.x, row = blockIdx.y, tid = threadIdx.x;
  __shared__ float4 yv4[kSplit4];      // staged y = logits / t  (32 KB)
  __shared__ int hist[kNB];            // 8 KB
  __shared__ int suf[kT1];
  __shared__ float mred[kT1], sred[kT1];
  __shared__ int bstar, scnt;

  const float t = temps[row];
  const size_t rowbase = (size_t)row * kV + (size_t)sp * kSplit;
  const float4* in4 = (const float4*)(logits + rowbase);
  float4* out4 = (float4*)(out + 2 * kB + rowbase);

  for (int i = tid; i < kNB; i += kT1) hist[i] = 0;
  if (tid == 0) scnt = 0;
  __syncthreads();

  // Pass 1: read logits once; stage y in LDS, online softmax, histogram,
  // zero-fill the output region for this split.
  float m = -INFINITY, s = 0.0f;
  const float4 z4 = make_float4(0.f, 0.f, 0.f, 0.f);
  for (int i = tid; i < kSplit4; i += kT1) {
    float4 l = in4[i];
    float4 y = make_float4(l.x / t, l.y / t, l.z / t, l.w / t);
    yv4[i] = y;
    out4[i] = z4;
    float vals[4] = {y.x, y.y, y.z, y.w};
#pragma unroll
    for (int j = 0; j < 4; ++j) {
      float yy = vals[j];
      if (yy <= m) {
        s += expf(yy - m);
      } else {
        s = s * expf(m - yy) + 1.0f;
        m = yy;
      }
      atomicAdd(&hist[fkey(yy) >> 21], 1);
    }
  }
  mred[tid] = m; sred[tid] = s;
  __syncthreads();
  // deterministic tree combine of (m, s)
  for (int off = kT1 / 2; off > 0; off >>= 1) {
    if (tid < off) {
      float m1 = mred[tid], m2 = mred[tid + off];
      float M = fmaxf(m1, m2);
      sred[tid] = sred[tid] * expf(m1 - M) + sred[tid + off] * expf(m2 - M);
      mred[tid] = M;
    }
    __syncthreads();
  }

  // Find threshold bucket b*: highest buckets cumulating >= kTop elements.
  const int c0 = tid * kChunk;
  int cs = 0;
#pragma unroll
  for (int j = 0; j < kChunk; ++j) cs += hist[c0 + j];
  suf[tid] = cs;
  __syncthreads();
  for (int off = 1; off < kT1; off <<= 1) {  // suffix-inclusive scan
    int v = (tid + off < kT1) ? suf[tid + off] : 0;
    __syncthreads();
    suf[tid] += v;
    __syncthreads();
  }
  const int sufN = (tid == kT1 - 1) ? 0 : suf[tid + 1];
  if (suf[tid] >= kTop && sufN < kTop) {  // exactly one thread
    int cum = sufN;
    for (int b = c0 + kChunk - 1; b >= c0; --b) {
      cum += hist[b];
      if (cum >= kTop) { bstar = b; break; }
    }
  }
  __syncthreads();

  // Pass 2 (from LDS): collect all elements with bucket >= b*  (exact
  // superset of this split's top-64; slot order via atomics is
  // nondeterministic but K2 fully re-sorts, so outputs are deterministic).
  const unsigned bs = (unsigned)bstar;
  const float* yv = (const float*)yv4;
  for (int i = tid; i < kSplit; i += kT1) {
    float y = yv[i];
    if ((fkey(y) >> 21) >= bs) {
      int pos = atomicAdd(&scnt, 1);
      if (pos < kCap) {
        size_t base = ((size_t)row * kSplits + sp) * kCap + pos;
        wv[base] = y;
        wi[base] = sp * kSplit + i;
      }
    }
  }
  __syncthreads();
  if (tid == 0) {
    wm[row * kSplits + sp] = mred[0];
    wS[row * kSplits + sp] = sred[0];
    wc[row * kSplits + sp] = scnt < kCap ? scnt : kCap;
  }
}

__global__ __launch_bounds__(64) void k_sample(
    const int* __restrict__ top_ks, const float* __restrict__ top_ps,
    const float* __restrict__ uin,
    const float* __restrict__ wm, const float* __restrict__ wS,
    const int* __restrict__ wc, const float* __restrict__ wv,
    const int* __restrict__ wi, float* __restrict__ out) {
  const int row = blockIdx.x, lane = threadIdx.x;
  __shared__ float cv[kSplits * kCap];
  __shared__ int ci[kSplits * kCap];
  __shared__ int off[kSplits + 1];
  __shared__ float tv[kTop];
  __shared__ int ti[kTop];
  __shared__ float sv[kTop];
  __shared__ float MS[2];

  if (lane == 0) {
    int o = 0;
    float M = -INFINITY;
    for (int s2 = 0; s2 < kSplits; ++s2) {
      off[s2] = o;
      o += wc[row * kSplits + s2];
      M = fmaxf(M, wm[row * kSplits + s2]);
    }
    off[kSplits] = o;
    float S = 0.f;
    for (int s2 = 0; s2 < kSplits; ++s2)
      S += expf(wm[row * kSplits + s2] - M) * wS[row * kSplits + s2];
    MS[0] = M; MS[1] = S;
  }
  __syncthreads();
  const int n = off[kSplits];
  for (int j = lane; j < n; j += 64) {
    int s2 = 0;
    while (j >= off[s2 + 1]) ++s2;
    size_t base = ((size_t)row * kSplits + s2) * kCap + (j - off[s2]);
    cv[j] = wv[base];
    ci[j] = wi[base];
  }
  __syncthreads();

  // 64 rounds of wave-level argmax; tie-break = smaller original index
  // (matches stable argsort of -probs in the reference).
  for (int r = 0; r < kTop; ++r) {
    float lv = -INFINITY; int li = 0x7fffffff; int lp = -1;
    for (int j = lane; j < n; j += 64) {
      float v = cv[j]; int idx = ci[j];
      if (v > lv || (v == lv && idx < li)) { lv = v; li = idx; lp = j; }
    }
    float rv = lv; int ri = li;
    for (int o2 = 32; o2 > 0; o2 >>= 1) {
      float ov = __shfl_down(rv, o2);
      int oi = __shfl_down(ri, o2);
      if (ov > rv || (ov == rv && oi < ri)) { rv = ov; ri = oi; }
    }
    rv = __shfl(rv, 0); ri = __shfl(ri, 0);
    if (lane == 0) { tv[r] = rv; ti[r] = ri; }
    if (lp >= 0 && lv == rv && li == ri) cv[lp] = -INFINITY;  // winner's lane clears it
    __syncthreads();
  }

  if (lane == 0) {
    const float M = MS[0], S = MS[1];
    const float tp = top_ps[row];
    const int kk = top_ks[row];
    const float uu = uin[row];
    float cum = 0.f;
    float qa[kTop];
#pragma unroll
    for (int r = 0; r < kTop; ++r) {
      float pr = expf(tv[r] - M) / S;          // prob of rank r
      cum += pr;
      float cb = cum - pr;                     // cumulative BEFORE this token
      qa[r] = ((cb > tp) || (r >= kk)) ? 0.f : pr;
    }
    const float q0 = qa[0];                    // rank 0 never masked
    float tot = 0.f;
    float cdfa[kTop];
#pragma unroll
    for (int r = 0; r < kTop; ++r) {
      float sr = qa[r] / q0;
      sv[r] = sr;
      tot += sr;
      cdfa[r] = tot;
    }
    const float rth = uu * tot;
    int cnt = 0;
#pragma unroll
    for (int r = 0; r < kTop; ++r) cnt += (cdfa[r] < rth) ? 1 : 0;
    if (cnt > kTop - 1) cnt = kTop - 1;
    out[row] = (float)ti[cnt];                 // sampled token id
    out[kB + row] = 1.0f;                      // success
  }
  __syncthreads();
  if (lane < kTop) out[2 * kB + (size_t)row * kV + lane] = sv[lane];
}
}  // namespace

extern "C" void kernel_launch(void* const* d_in, const int* in_sizes, int n_in,
                              void* d_out, int out_size, void* d_ws, size_t ws_size,
                              hipStream_t stream) {
  const float* logits = (const float*)d_in[0];
  const float* temps  = (const float*)d_in[1];
  const int*   top_ks = (const int*)d_in[2];
  const float* top_ps = (const float*)d_in[3];
  const float* uin    = (const float*)d_in[4];
  float* out = (float*)d_out;

  // workspace layout (~4.2 MB)
  float* wm = (float*)d_ws;                          // [B*Splits] split max
  float* wS = wm + kB * kSplits;                     // [B*Splits] split sumexp
  int*   wc = (int*)(wS + kB * kSplits);             // [B*Splits] candidate count
  float* wv = (float*)(wc + kB * kSplits);           // [B*Splits*Cap] cand value
  int*   wi = (int*)(wv + (size_t)kB * kSplits * kCap);  // [B*Splits*Cap] cand index

  k_select<<<dim3(kSplits, kB), kT1, 0, stream>>>(logits, temps, out, wm, wS, wc, wv, wi);
  k_sample<<<kB, 64, 0, stream>>>(top_ks, top_ps, uin, wm, wS, wc, wv, wi, out);
}

// Round 2
// 126.102 us; speedup vs baseline: 3.4244x; 3.4244x over previous
//
#include <hip/hip_runtime.h>
#include <math.h>

namespace {
constexpr int kB = 128;
constexpr int kV = 128256;
constexpr int kSplits = 16;
constexpr int kSplit = kV / kSplits;   // 8016
constexpr int kSplit4 = kSplit / 4;    // 2004
constexpr int kT1 = 256;
constexpr int kNB = 2048;              // histogram buckets (11-bit key prefix)
constexpr int kChunk = kNB / kT1;      // 8 buckets per thread
constexpr int kCap = 512;              // max candidates kept per split (pow2)
constexpr int kTop = 64;               // max top_k

// monotonic uint key: ascending key <=> ascending float
__device__ __forceinline__ unsigned fkey(float y) {
  unsigned u = __float_as_uint(y);
  return ((int)u < 0) ? ~u : (u | 0x80000000u);
}
__device__ __forceinline__ float keyinv(unsigned k) {
  unsigned u = (k & 0x80000000u) ? (k & 0x7fffffffu) : ~k;
  return __uint_as_float(u);
}

__global__ __launch_bounds__(kT1) void k_select(
    const float* __restrict__ logits, const float* __restrict__ temps,
    float* __restrict__ out,
    float* __restrict__ wm, float* __restrict__ wS,
    unsigned long long* __restrict__ wpk) {
  const int sp = blockIdx.x, row = blockIdx.y, tid = threadIdx.x;
  __shared__ float4 yv4[kSplit4];      // staged y = logits / t  (32 KB)
  __shared__ union U {                 // hist first, then candidate sort (8 KB)
    int hist[kNB];
    unsigned long long cand[kCap];
  } u;
  __shared__ int suf[kT1];
  __shared__ float mred[kT1], sred[kT1];
  __shared__ int bstar, scnt;

  const float t = temps[row];
  const size_t rowbase = (size_t)row * kV + (size_t)sp * kSplit;
  const float4* in4 = (const float4*)(logits + rowbase);
  float4* out4 = (float4*)(out + 2 * kB + rowbase);

  for (int i = tid; i < kNB; i += kT1) u.hist[i] = 0;
  if (tid == 0) scnt = 0;
  __syncthreads();

  // Pass 1: read logits once; stage y in LDS, online softmax, histogram,
  // zero-fill the output region for this split.
  float m = -INFINITY, s = 0.0f;
  const float4 z4 = make_float4(0.f, 0.f, 0.f, 0.f);
  for (int i = tid; i < kSplit4; i += kT1) {
    float4 l = in4[i];
    float4 y = make_float4(l.x / t, l.y / t, l.z / t, l.w / t);
    yv4[i] = y;
    out4[i] = z4;
    float vals[4] = {y.x, y.y, y.z, y.w};
#pragma unroll
    for (int j = 0; j < 4; ++j) {
      float yy = vals[j];
      if (yy <= m) {
        s += expf(yy - m);
      } else {
        s = s * expf(m - yy) + 1.0f;
        m = yy;
      }
      atomicAdd(&u.hist[fkey(yy) >> 21], 1);
    }
  }
  mred[tid] = m; sred[tid] = s;
  __syncthreads();
  // deterministic tree combine of (m, s)
  for (int off = kT1 / 2; off > 0; off >>= 1) {
    if (tid < off) {
      float m1 = mred[tid], m2 = mred[tid + off];
      float M = fmaxf(m1, m2);
      sred[tid] = sred[tid] * expf(m1 - M) + sred[tid + off] * expf(m2 - M);
      mred[tid] = M;
    }
    __syncthreads();
  }

  // Threshold bucket b*: highest bucket whose suffix count >= kTop.
  const int c0 = tid * kChunk;
  int cs = 0;
#pragma unroll
  for (int j = 0; j < kChunk; ++j) cs += u.hist[c0 + j];
  suf[tid] = cs;
  __syncthreads();
  for (int off = 1; off < kT1; off <<= 1) {  // suffix-inclusive scan
    int v = (tid + off < kT1) ? suf[tid + off] : 0;
    __syncthreads();
    suf[tid] += v;
    __syncthreads();
  }
  const int sufN = (tid == kT1 - 1) ? 0 : suf[tid + 1];
  if (suf[tid] >= kTop && sufN < kTop) {  // exactly one thread
    int cum = sufN;
    for (int b = c0 + kChunk - 1; b >= c0; --b) {
      cum += u.hist[b];
      if (cum >= kTop) { bstar = b; break; }
    }
  }
  __syncthreads();   // hist reads done; u.cand may now alias

  // Pass 2 (from LDS): collect all elements with bucket >= b*  (exact
  // superset of this split's top-64). Pack (key, ~idx) so u64 descending
  // order == value desc, index asc (matches stable argsort of -probs).
  const unsigned bs = (unsigned)bstar;
  const float* yv = (const float*)yv4;
  for (int i = tid; i < kSplit; i += kT1) {
    unsigned key = fkey(yv[i]);
    if ((key >> 21) >= bs) {
      int pos = atomicAdd(&scnt, 1);
      if (pos < kCap) {
        u.cand[pos] = ((unsigned long long)key << 32) |
                      (unsigned)(~(unsigned)(sp * kSplit + i));
      }
    }
  }
  __syncthreads();
  const int nc = scnt < kCap ? scnt : kCap;
  for (int i = tid; i < kCap; i += kT1)
    if (i >= nc) u.cand[i] = 0ULL;

  // Bitonic sort, descending, kCap entries, 2 per thread.
  for (int kk = 2; kk <= kCap; kk <<= 1) {
    for (int j = kk >> 1; j > 0; j >>= 1) {
      __syncthreads();
#pragma unroll
      for (int e = 0; e < kCap / kT1; ++e) {
        int i = tid + e * kT1;
        int ixj = i ^ j;
        if (ixj > i) {
          unsigned long long a = u.cand[i], b = u.cand[ixj];
          bool desc = ((i & kk) == 0);
          if (desc ? (a < b) : (a > b)) { u.cand[i] = b; u.cand[ixj] = a; }
        }
      }
    }
  }
  __syncthreads();

  if (tid < kTop)
    wpk[((size_t)row * kSplits + sp) * kTop + tid] = u.cand[tid];
  if (tid == 0) {
    wm[row * kSplits + sp] = mred[0];
    wS[row * kSplits + sp] = sred[0];
  }
}

__global__ __launch_bounds__(kT1) void k_sample(
    const int* __restrict__ top_ks, const float* __restrict__ top_ps,
    const float* __restrict__ uin,
    const float* __restrict__ wm, const float* __restrict__ wS,
    const unsigned long long* __restrict__ wpk, float* __restrict__ out) {
  const int row = blockIdx.x, tid = threadIdx.x;
  constexpr int kN = kSplits * kTop;   // 1024
  __shared__ unsigned long long pk[kN];
  __shared__ float mArr[kSplits], sArr[kSplits];
  __shared__ float tv[kTop];
  __shared__ int ti[kTop];
  __shared__ float sv[kTop];
  __shared__ float MS[2];

  if (tid < kSplits) {
    mArr[tid] = wm[row * kSplits + tid];
    sArr[tid] = wS[row * kSplits + tid];
  }
  for (int i = tid; i < kN; i += kT1)
    pk[i] = wpk[(size_t)row * kN + i];
  __syncthreads();
  if (tid == 0) {  // fixed-order merge of split (m, S) partials
    float M = -INFINITY;
    for (int s2 = 0; s2 < kSplits; ++s2) M = fmaxf(M, mArr[s2]);
    float S = 0.f;
    for (int s2 = 0; s2 < kSplits; ++s2) S += expf(mArr[s2] - M) * sArr[s2];
    MS[0] = M; MS[1] = S;
  }

  // Bitonic sort, descending, 1024 entries, 4 per thread.
  for (int kk = 2; kk <= kN; kk <<= 1) {
    for (int j = kk >> 1; j > 0; j >>= 1) {
      __syncthreads();
#pragma unroll
      for (int e = 0; e < kN / kT1; ++e) {
        int i = tid + e * kT1;
        int ixj = i ^ j;
        if (ixj > i) {
          unsigned long long a = pk[i], b = pk[ixj];
          bool desc = ((i & kk) == 0);
          if (desc ? (a < b) : (a > b)) { pk[i] = b; pk[ixj] = a; }
        }
      }
    }
  }
  __syncthreads();

  if (tid < kTop) {
    unsigned long long p2 = pk[tid];
    tv[tid] = keyinv((unsigned)(p2 >> 32));
    ti[tid] = (int)(~(unsigned)(p2 & 0xffffffffu));
  }
  __syncthreads();

  if (tid == 0) {  // exact reference-order serial epilogue (absmax 0 in R1)
    const float M = MS[0], S = MS[1];
    const float tp = top_ps[row];
    const int kk = top_ks[row];
    const float uu = uin[row];
    float cum = 0.f;
    float qa[kTop];
#pragma unroll
    for (int r = 0; r < kTop; ++r) {
      float pr = expf(tv[r] - M) / S;          // prob of rank r
      cum += pr;
      float cb = cum - pr;                     // cumulative BEFORE this token
      qa[r] = ((cb > tp) || (r >= kk)) ? 0.f : pr;
    }
    const float q0 = qa[0];                    // rank 0 never masked
    float tot = 0.f;
    float cdfa[kTop];
#pragma unroll
    for (int r = 0; r < kTop; ++r) {
      float sr = qa[r] / q0;
      sv[r] = sr;
      tot += sr;
      cdfa[r] = tot;
    }
    const float rth = uu * tot;
    int cnt = 0;
#pragma unroll
    for (int r = 0; r < kTop; ++r) cnt += (cdfa[r] < rth) ? 1 : 0;
    if (cnt > kTop - 1) cnt = kTop - 1;
    out[row] = (float)ti[cnt];                 // sampled token id
    out[kB + row] = 1.0f;                      // success
  }
  __syncthreads();
  if (tid < kTop) out[2 * kB + (size_t)row * kV + tid] = sv[tid];
}
}  // namespace

extern "C" void kernel_launch(void* const* d_in, const int* in_sizes, int n_in,
                              void* d_out, int out_size, void* d_ws, size_t ws_size,
                              hipStream_t stream) {
  const float* logits = (const float*)d_in[0];
  const float* temps  = (const float*)d_in[1];
  const int*   top_ks = (const int*)d_in[2];
  const float* top_ps = (const float*)d_in[3];
  const float* uin    = (const float*)d_in[4];
  float* out = (float*)d_out;

  // workspace layout (~1.1 MB)
  float* wm = (float*)d_ws;                          // [B*Splits] split max
  float* wS = wm + kB * kSplits;                     // [B*Splits] split sumexp
  unsigned long long* wpk =                          // [B*Splits*Top] sorted top-64
      (unsigned long long*)(wS + kB * kSplits + kB * kSplits);  // (8B aligned)

  k_select<<<dim3(kSplits, kB), kT1, 0, stream>>>(logits, temps, out, wm, wS, wpk);
  k_sample<<<kB, kT1, 0, stream>>>(top_ks, top_ps, uin, wm, wS, wpk, out);
}

// Round 3
// 63.308 us; speedup vs baseline: 6.8211x; 1.9919x over previous
//
#include <hip/hip_runtime.h>
#include <math.h>

namespace {
constexpr int kB = 128;
constexpr int kV = 128256;
constexpr int kSplits = 16;
constexpr int kSplit = kV / kSplits;   // 8016
constexpr int kSplit4 = kSplit / 4;    // 2004 float4
constexpr int kT1 = 256;
constexpr int kE = 8;                  // float4 regs/thread: 8*256=2048 >= 2004
constexpr int kCap = 256;              // candidate cap (== kT1, 1 per thread)
constexpr int kTop = 64;               // max top_k

// monotonic uint key: ascending key <=> ascending float
__device__ __forceinline__ unsigned fkey(float y) {
  unsigned u = __float_as_uint(y);
  return ((int)u < 0) ? ~u : (u | 0x80000000u);
}
__device__ __forceinline__ float keyinv(unsigned k) {
  unsigned u = (k & 0x80000000u) ? (k & 0x7fffffffu) : ~k;
  return __uint_as_float(u);
}

__global__ __launch_bounds__(kT1) void k_select(
    const float* __restrict__ logits, const float* __restrict__ temps,
    float* __restrict__ out,
    float* __restrict__ wm, float* __restrict__ wS,
    unsigned long long* __restrict__ wpk) {
  const int sp = blockIdx.x, row = blockIdx.y, tid = threadIdx.x;
  const int lane = tid & 63, wid = tid >> 6;
  __shared__ float red[kT1];
  __shared__ int ired[4];
  __shared__ unsigned long long cand[kCap];
  __shared__ int scnt;

  if (tid == 0) scnt = 0;
  const float t = temps[row];
  const size_t rowbase = (size_t)row * kV + (size_t)sp * kSplit;
  const float4* in4 = (const float4*)(logits + rowbase);
  float4* out4 = (float4*)(out + 2 * kB + rowbase);
  const float4 z4 = make_float4(0.f, 0.f, 0.f, 0.f);
  const float nI = -INFINITY;

  // Load split into registers; zero-fill output; running max.
  float4 r[kE];
  float m = nI;
#pragma unroll
  for (int e = 0; e < kE; ++e) {
    int f = tid + e * kT1;
    float4 l;
    if (f < kSplit4) { l = in4[f]; out4[f] = z4; }
    else l = make_float4(nI, nI, nI, nI);
    float4 y = make_float4(l.x / t, l.y / t, l.z / t, l.w / t);
    r[e] = y;
    m = fmaxf(m, fmaxf(fmaxf(y.x, y.y), fmaxf(y.z, y.w)));
  }
  red[tid] = m; __syncthreads();
  for (int off = kT1 / 2; off; off >>= 1) {
    if (tid < off) red[tid] = fmaxf(red[tid], red[tid + off]);
    __syncthreads();
  }
  const float M = red[0];
  __syncthreads();

  // Exact branch-free sum of exp(y - M); deterministic order (pads add 0).
  float s = 0.f;
#pragma unroll
  for (int e = 0; e < kE; ++e) {
    s += expf(r[e].x - M); s += expf(r[e].y - M);
    s += expf(r[e].z - M); s += expf(r[e].w - M);
  }
  red[tid] = s; __syncthreads();
  for (int off = kT1 / 2; off; off >>= 1) {
    if (tid < off) red[tid] += red[tid + off];
    __syncthreads();
  }
  const float Ssp = red[0];

  // Convert registers in place to monotonic keys (pad key = 0x007FFFFF < lo).
#pragma unroll
  for (int e = 0; e < kE; ++e) {
    r[e].x = __uint_as_float(fkey(r[e].x));
    r[e].y = __uint_as_float(fkey(r[e].y));
    r[e].z = __uint_as_float(fkey(r[e].z));
    r[e].w = __uint_as_float(fkey(r[e].w));
  }

  // Binary-search threshold T with count(key >= T) in [kTop, kCap].
  unsigned lo = 0x00800000u;          // >= all finite y; excludes -inf pads
  unsigned hi = fkey(M) + 1;          // count 0
  for (int it = 0; it < 32 && hi - lo > 1; ++it) {
    unsigned mid = lo + ((hi - lo) >> 1);
    int c = 0;
#pragma unroll
    for (int e = 0; e < kE; ++e) {
      c += (__float_as_uint(r[e].x) >= mid);
      c += (__float_as_uint(r[e].y) >= mid);
      c += (__float_as_uint(r[e].z) >= mid);
      c += (__float_as_uint(r[e].w) >= mid);
    }
    for (int o = 32; o; o >>= 1) c += __shfl_down(c, o);
    if (lane == 0) ired[wid] = c;
    __syncthreads();
    c = ired[0] + ired[1] + ired[2] + ired[3];
    __syncthreads();
    if (c >= kTop) { lo = mid; if (c <= kCap) break; }
    else hi = mid;
  }
  const unsigned T = lo;

  // Collect candidates (<= kCap in practice); pack (key, ~idx) so u64 desc
  // order == value desc, index asc (stable argsort of -probs tie-break).
#pragma unroll
  for (int e = 0; e < kE; ++e) {
    int f = tid + e * kT1;
#pragma unroll
    for (int j = 0; j < 4; ++j) {
      unsigned key = __float_as_uint(j == 0 ? r[e].x : j == 1 ? r[e].y
                                   : j == 2 ? r[e].z : r[e].w);
      if (key >= T) {
        int pos = atomicAdd(&scnt, 1);
        if (pos < kCap)
          cand[pos] = ((unsigned long long)key << 32) |
                      (unsigned)~(unsigned)(sp * kSplit + f * 4 + j);
      }
    }
  }
  __syncthreads();
  if (tid >= (scnt < kCap ? scnt : kCap)) cand[tid] = 0ULL;

  // Bitonic sort 256 desc, one element per thread.
  for (int k2 = 2; k2 <= kCap; k2 <<= 1)
    for (int j = k2 >> 1; j; j >>= 1) {
      __syncthreads();
      int ixj = tid ^ j;
      if (ixj > tid) {
        unsigned long long a = cand[tid], b = cand[ixj];
        bool desc = ((tid & k2) == 0);
        if (desc ? (a < b) : (a > b)) { cand[tid] = b; cand[ixj] = a; }
      }
    }
  __syncthreads();

  if (tid < kTop)
    wpk[((size_t)row * kSplits + sp) * kTop + tid] = cand[tid];
  if (tid == 0) {
    wm[row * kSplits + sp] = M;
    wS[row * kSplits + sp] = Ssp;
  }
}

__global__ __launch_bounds__(kT1) void k_sample(
    const int* __restrict__ top_ks, const float* __restrict__ top_ps,
    const float* __restrict__ uin,
    const float* __restrict__ wm, const float* __restrict__ wS,
    const unsigned long long* __restrict__ wpk, float* __restrict__ out) {
  const int row = blockIdx.x, tid = threadIdx.x;
  constexpr int kN = kSplits * kTop;   // 1024
  __shared__ unsigned long long pk[kN];
  __shared__ float mArr[kSplits], sArr[kSplits];
  __shared__ float tv[kTop];
  __shared__ int ti[kTop];
  __shared__ float sv[kTop];
  __shared__ float MS[2];

  if (tid < kSplits) {
    mArr[tid] = wm[row * kSplits + tid];
    sArr[tid] = wS[row * kSplits + tid];
  }
  for (int i = tid; i < kN; i += kT1)
    pk[i] = wpk[(size_t)row * kN + i];
  __syncthreads();
  if (tid == 0) {  // fixed-order merge of split (m, S) partials
    float M = -INFINITY;
    for (int s2 = 0; s2 < kSplits; ++s2) M = fmaxf(M, mArr[s2]);
    float S = 0.f;
    for (int s2 = 0; s2 < kSplits; ++s2) S += expf(mArr[s2] - M) * sArr[s2];
    MS[0] = M; MS[1] = S;
  }

  // Bitonic top-64 merge: 4 rounds of (cross-compare + 6 cleanup stages).
  // Runs of 64 sorted desc start at q*(128<<r); partner run at +(64<<r).
  for (int r = 0; r < 4; ++r) {
    const int pairs = 8 >> r;
    __syncthreads();
    for (int w = tid; w < pairs * 64; w += kT1) {
      int q = w >> 6, i = w & 63;
      int a = q * (128 << r), b = a + (64 << r);
      unsigned long long x = pk[a + i], y = pk[b + 63 - i];
      pk[a + i] = x > y ? x : y;      // top-64 multiset, bitonic order
    }
    for (int j = 32; j; j >>= 1) {    // desc bitonic merge of each kept run
      __syncthreads();
      for (int w = tid; w < pairs * 32; w += kT1) {
        int q = w >> 5, z = w & 31;
        int a = q * (128 << r);
        int i = ((z & ~(j - 1)) << 1) | (z & (j - 1));
        unsigned long long x = pk[a + i], y = pk[a + i + j];
        if (x < y) { pk[a + i] = y; pk[a + i + j] = x; }
      }
    }
  }
  __syncthreads();

  if (tid < kTop) {
    unsigned long long p2 = pk[tid];
    tv[tid] = keyinv((unsigned)(p2 >> 32));
    ti[tid] = (int)(~(unsigned)(p2 & 0xffffffffu));
  }
  __syncthreads();

  if (tid == 0) {  // exact reference-order serial epilogue (absmax 0 twice)
    const float M = MS[0], S = MS[1];
    const float tp = top_ps[row];
    const int kk = top_ks[row];
    const float uu = uin[row];
    float cum = 0.f;
    float qa[kTop];
#pragma unroll
    for (int r = 0; r < kTop; ++r) {
      float pr = expf(tv[r] - M) / S;          // prob of rank r
      cum += pr;
      float cb = cum - pr;                     // cumulative BEFORE this token
      qa[r] = ((cb > tp) || (r >= kk)) ? 0.f : pr;
    }
    const float q0 = qa[0];                    // rank 0 never masked
    float tot = 0.f;
    float cdfa[kTop];
#pragma unroll
    for (int r = 0; r < kTop; ++r) {
      float sr = qa[r] / q0;
      sv[r] = sr;
      tot += sr;
      cdfa[r] = tot;
    }
    const float rth = uu * tot;
    int cnt = 0;
#pragma unroll
    for (int r = 0; r < kTop; ++r) cnt += (cdfa[r] < rth) ? 1 : 0;
    if (cnt > kTop - 1) cnt = kTop - 1;
    out[row] = (float)ti[cnt];                 // sampled token id
    out[kB + row] = 1.0f;                      // success
  }
  __syncthreads();
  if (tid < kTop) out[2 * kB + (size_t)row * kV + tid] = sv[tid];
}
}  // namespace

extern "C" void kernel_launch(void* const* d_in, const int* in_sizes, int n_in,
                              void* d_out, int out_size, void* d_ws, size_t ws_size,
                              hipStream_t stream) {
  const float* logits = (const float*)d_in[0];
  const float* temps  = (const float*)d_in[1];
  const int*   top_ks = (const int*)d_in[2];
  const float* top_ps = (const float*)d_in[3];
  const float* uin    = (const float*)d_in[4];
  float* out = (float*)d_out;

  // workspace layout (~1.1 MB)
  float* wm = (float*)d_ws;                          // [B*Splits] split max
  float* wS = wm + kB * kSplits;                     // [B*Splits] split sumexp
  unsigned long long* wpk =                          // [B*Splits*Top] sorted top-64
      (unsigned long long*)(wS + kB * kSplits + kB * kSplits);

  k_select<<<dim3(kSplits, kB), kT1, 0, stream>>>(logits, temps, out, wm, wS, wpk);
  k_sample<<<kB, kT1, 0, stream>>>(top_ks, top_ps, uin, wm, wS, wpk, out);
}